// Round 1
// baseline (151.554 us; speedup 1.0000x reference)
//
#include <hip/hip_runtime.h>
#include <cstddef>

#define EPS 1e-5f

constexpr int NG  = 8192;   // genes
constexpr int HID = 32768;  // hidden (= NG*4)
constexpr int NTF = 1024;   // TFs
constexpr int B   = 256;    // batch

// ---------------------------------------------------------------------------
// Kernel 1: fused  sparse-L1 -> relu -> BN1 -> sparse-L2(4x4 blockdiag) -> relu
// plus BN2 stats.  Writes relu(h2) TRANSPOSED [HID][B] so layer-3's gather is
// coalesced, and per-column (mean2, invstd2) for folding BN2 into layer 3.
//
// Block = 256 threads = 64 columns x 4 batch-slices of 64.
// BN1/BN2 stats are gene-local, so everything stays inside the block.
// ---------------------------------------------------------------------------
__global__ __launch_bounds__(256) void fused12(
    const float* __restrict__ x,   // [B][NG]
    const float* __restrict__ w1,  // [HID]
    const float* __restrict__ b1,  // [HID]
    const float* __restrict__ w2,  // [HID*4]
    const float* __restrict__ b2,  // [HID]
    float* __restrict__ h2rT,      // [HID][B]
    float* __restrict__ m2g,       // [HID]
    float* __restrict__ inv2g)     // [HID]
{
    const int lane  = threadIdx.x & 63;   // column within block tile
    const int slice = threadIdx.x >> 6;   // which 64-row batch slice
    const int c     = (blockIdx.x << 6) + lane;  // global hidden column
    const int g     = c >> 2;             // gene
    const int b0    = slice << 6;

    __shared__ float redA[4][64], redB[4][64];
    __shared__ float m1s[64], inv1s[64];

    const float w1c = w1[c], b1c = b1[c];
    const float* xp = x + (size_t)b0 * NG + g;

    // ---- phase A: BN1 stats for column c over this thread's 64 rows ----
    float s = 0.f, s2 = 0.f;
    #pragma unroll 8
    for (int i = 0; i < 64; ++i) {
        float h = fmaxf(fmaf(w1c, xp[(size_t)i * NG], b1c), 0.f);
        s += h;
        s2 = fmaf(h, h, s2);
    }
    redA[slice][lane] = s;
    redB[slice][lane] = s2;
    __syncthreads();
    if (slice == 0) {
        float S  = redA[0][lane] + redA[1][lane] + redA[2][lane] + redA[3][lane];
        float S2 = redB[0][lane] + redB[1][lane] + redB[2][lane] + redB[3][lane];
        float m  = S * (1.f / 256.f);
        float v  = fmaf(-m, m, S2 * (1.f / 256.f));
        m1s[lane]   = m;
        inv1s[lane] = rsqrtf(v + EPS);
    }
    __syncthreads();

    // ---- fold BN1 into the 4x4 block weights ----
    const int lbase = lane & ~3;   // first column of my gene in LDS tile
    const int gbase = g << 2;      // first global column of my gene
    float w1j[4], b1j[4], w2s[4];
    float bconst = b2[c];
    #pragma unroll
    for (int j = 0; j < 4; ++j) {
        w1j[j] = w1[gbase + j];
        b1j[j] = b1[gbase + j];
        float wv = w2[(c << 2) + j] * inv1s[lbase + j];
        w2s[j] = wv;
        bconst = fmaf(-wv, m1s[lbase + j], bconst);
    }

    // ---- phase B: recompute h1, apply folded L2, relu, BN2 stats, store ----
    float t2s = 0.f, t2s2 = 0.f;
    float* op = h2rT + (size_t)c * B + b0;
    for (int i0 = 0; i0 < 64; i0 += 4) {
        float rr[4];
        #pragma unroll
        for (int u = 0; u < 4; ++u) {
            float v = xp[(size_t)(i0 + u) * NG];
            float acc = bconst;
            #pragma unroll
            for (int j = 0; j < 4; ++j) {
                float r = fmaxf(fmaf(w1j[j], v, b1j[j]), 0.f);
                acc = fmaf(w2s[j], r, acc);
            }
            float r2 = fmaxf(acc, 0.f);
            t2s += r2;
            t2s2 = fmaf(r2, r2, t2s2);
            rr[u] = r2;
        }
        *(float4*)(op + i0) = make_float4(rr[0], rr[1], rr[2], rr[3]);
    }

    __syncthreads();                 // redA/redB reads from phase A are done
    redA[slice][lane] = t2s;
    redB[slice][lane] = t2s2;
    __syncthreads();
    if (slice == 0) {
        float S  = redA[0][lane] + redA[1][lane] + redA[2][lane] + redA[3][lane];
        float S2 = redB[0][lane] + redB[1][lane] + redB[2][lane] + redB[3][lane];
        float m  = S * (1.f / 256.f);
        float v  = fmaf(-m, m, S2 * (1.f / 256.f));
        m2g[c]   = m;
        inv2g[c] = rsqrtf(v + EPS);
    }
}

// ---------------------------------------------------------------------------
// Kernel 2: layer 3 gather-dot (BN2 folded into weights) + BN3 + output.
// Block = one TF t; thread = one batch row b. Gathered columns are contiguous
// 1 KiB runs in h2rT -> fully coalesced reads.
// ---------------------------------------------------------------------------
__global__ __launch_bounds__(256) void fused3(
    const float* __restrict__ h2rT,   // [HID][B]
    const float* __restrict__ m2g,    // [HID]
    const float* __restrict__ inv2g,  // [HID]
    const float* __restrict__ w3,     // [NTF*256]
    const float* __restrict__ b3,     // [NTF]
    const int*   __restrict__ cols3,  // [NTF*256]
    float* __restrict__ out)          // [B][NTF]
{
    const int t   = blockIdx.x;
    const int tid = threadIdx.x;      // batch row

    __shared__ float wls[256];
    __shared__ int   als[256];
    __shared__ float wred[4], rs[4], rs2[4];

    // fold BN2 into w3; accumulate bias correction
    int   col = cols3[(t << 8) + tid];
    float iv  = inv2g[col];
    float wv  = w3[(t << 8) + tid] * iv;
    wls[tid]  = wv;
    als[tid]  = col << 8;             // col * B
    float bp  = wv * m2g[col];
    #pragma unroll
    for (int o = 32; o > 0; o >>= 1) bp += __shfl_xor(bp, o);
    if ((tid & 63) == 0) wred[tid >> 6] = bp;
    __syncthreads();
    const float zbias = b3[t] - (wred[0] + wred[1] + wred[2] + wred[3]);

    // 256-deep dot: LDS broadcasts + coalesced global column reads
    float acc = 0.f;
    #pragma unroll 8
    for (int e = 0; e < 256; ++e)
        acc = fmaf(wls[e], h2rT[(size_t)(als[e] + tid)], acc);
    float z = acc + zbias;

    // BN3 over the 256 batch rows (this block)
    float s = z, s2 = z * z;
    #pragma unroll
    for (int o = 32; o > 0; o >>= 1) {
        s  += __shfl_xor(s, o);
        s2 += __shfl_xor(s2, o);
    }
    if ((tid & 63) == 0) { rs[tid >> 6] = s; rs2[tid >> 6] = s2; }
    __syncthreads();
    float S  = rs[0] + rs[1] + rs[2] + rs[3];
    float S2 = rs2[0] + rs2[1] + rs2[2] + rs2[3];
    float m  = S * (1.f / 256.f);
    float v  = fmaf(-m, m, S2 * (1.f / 256.f));
    float invs = rsqrtf(v + EPS);
    out[(size_t)tid * NTF + t] = (z - m) * invs;
}

// ---------------------------------------------------------------------------
extern "C" void kernel_launch(void* const* d_in, const int* in_sizes, int n_in,
                              void* d_out, int out_size, void* d_ws, size_t ws_size,
                              hipStream_t stream) {
    const float* x   = (const float*)d_in[0];
    const float* w1  = (const float*)d_in[1];
    const float* b1  = (const float*)d_in[2];
    const float* w2  = (const float*)d_in[3];
    const float* b2  = (const float*)d_in[4];
    const float* w3  = (const float*)d_in[5];
    const float* b3  = (const float*)d_in[6];
    const int* cols3 = (const int*)d_in[12];
    float* out = (float*)d_out;

    // workspace: h2rT [HID*B] f32 (33.5 MB) + m2 [HID] + inv2 [HID]
    float* ws    = (float*)d_ws;
    float* h2rT  = ws;
    float* m2g   = ws + (size_t)HID * B;
    float* inv2g = m2g + HID;

    fused12<<<HID / 64, 256, 0, stream>>>(x, w1, b1, w2, b2, h2rT, m2g, inv2g);
    fused3<<<NTF, 256, 0, stream>>>(h2rT, m2g, inv2g, w3, b3, cols3, out);
}

// Round 2
// 117.939 us; speedup vs baseline: 1.2850x; 1.2850x over previous
//
#include <hip/hip_runtime.h>
#include <cstddef>

#define EPS 1e-5f

constexpr int NG  = 8192;   // genes
constexpr int HID = 32768;  // hidden (= NG*4)
constexpr int NTF = 1024;   // TFs
constexpr int B   = 256;    // batch

// round-to-nearest-even f32 -> bf16 bits (no NaN inputs in this problem)
static __device__ __forceinline__ unsigned short f2bf(float v) {
    union { float f; unsigned u; } a; a.f = v;
    unsigned r = a.u + 0x7fffu + ((a.u >> 16) & 1u);
    return (unsigned short)(r >> 16);
}

// ---------------------------------------------------------------------------
// Kernel 1: fused  sparse-L1 -> relu -> BN1 -> sparse-L2(4x4 blockdiag) -> relu
// Writes relu(h2) TRANSPOSED [HID][B] in bf16 (coalesced gather for layer 3),
// plus per-column (mean2, invstd2) so BN2 folds into layer-3 weights.
//
// Block = 256 threads = 64 columns x 4 batch-slices of 64. BN1/BN2 stats are
// gene-local, so everything stays inside the block.
// ---------------------------------------------------------------------------
__global__ __launch_bounds__(256) void fused12(
    const float* __restrict__ x,       // [B][NG]
    const float* __restrict__ w1,      // [HID]
    const float* __restrict__ b1,      // [HID]
    const float* __restrict__ w2,      // [HID*4]
    const float* __restrict__ b2,      // [HID]
    unsigned short* __restrict__ h2rT, // [HID][B] bf16 bits
    float* __restrict__ m2g,           // [HID]
    float* __restrict__ inv2g)         // [HID]
{
    const int lane  = threadIdx.x & 63;   // column within block tile
    const int slice = threadIdx.x >> 6;   // which 64-row batch slice
    const int c     = (blockIdx.x << 6) + lane;  // global hidden column
    const int g     = c >> 2;             // gene
    const int b0    = slice << 6;

    __shared__ float redA[4][64], redB[4][64];
    __shared__ float m1s[64], inv1s[64];

    const float w1c = w1[c], b1c = b1[c];
    const float* xp = x + (size_t)b0 * NG + g;

    // ---- phase A: BN1 stats for column c over this thread's 64 rows ----
    float s = 0.f, s2 = 0.f;
    #pragma unroll 8
    for (int i = 0; i < 64; ++i) {
        float h = fmaxf(fmaf(w1c, xp[(size_t)i * NG], b1c), 0.f);
        s += h;
        s2 = fmaf(h, h, s2);
    }
    redA[slice][lane] = s;
    redB[slice][lane] = s2;
    __syncthreads();
    if (slice == 0) {
        float S  = redA[0][lane] + redA[1][lane] + redA[2][lane] + redA[3][lane];
        float S2 = redB[0][lane] + redB[1][lane] + redB[2][lane] + redB[3][lane];
        float m  = S * (1.f / 256.f);
        float v  = fmaf(-m, m, S2 * (1.f / 256.f));
        m1s[lane]   = m;
        inv1s[lane] = rsqrtf(v + EPS);
    }
    __syncthreads();

    // ---- fold BN1 into the 4x4 block weights ----
    const int lbase = lane & ~3;   // first column of my gene in LDS tile
    const int gbase = g << 2;      // first global column of my gene
    float w1j[4], b1j[4], w2s[4];
    float bconst = b2[c];
    #pragma unroll
    for (int j = 0; j < 4; ++j) {
        w1j[j] = w1[gbase + j];
        b1j[j] = b1[gbase + j];
        float wv = w2[(c << 2) + j] * inv1s[lbase + j];
        w2s[j] = wv;
        bconst = fmaf(-wv, m1s[lbase + j], bconst);
    }

    // ---- phase B: recompute h1, folded L2, relu, BN2 stats, bf16 store ----
    float t2s = 0.f, t2s2 = 0.f;
    unsigned short* op = h2rT + (size_t)c * B + b0;
    for (int i0 = 0; i0 < 64; i0 += 4) {
        ushort4 pk;
        unsigned short* pp = (unsigned short*)&pk;
        #pragma unroll
        for (int u = 0; u < 4; ++u) {
            float v = xp[(size_t)(i0 + u) * NG];
            float acc = bconst;
            #pragma unroll
            for (int j = 0; j < 4; ++j) {
                float r = fmaxf(fmaf(w1j[j], v, b1j[j]), 0.f);
                acc = fmaf(w2s[j], r, acc);
            }
            float r2 = fmaxf(acc, 0.f);
            t2s += r2;
            t2s2 = fmaf(r2, r2, t2s2);
            pp[u] = f2bf(r2);
        }
        *(ushort4*)(op + i0) = pk;   // 8 B store, aligned
    }

    __syncthreads();                 // phase-A reads of redA/redB done
    redA[slice][lane] = t2s;
    redB[slice][lane] = t2s2;
    __syncthreads();
    if (slice == 0) {
        float S  = redA[0][lane] + redA[1][lane] + redA[2][lane] + redA[3][lane];
        float S2 = redB[0][lane] + redB[1][lane] + redB[2][lane] + redB[3][lane];
        float m  = S * (1.f / 256.f);
        float v  = fmaf(-m, m, S2 * (1.f / 256.f));
        m2g[c]   = m;
        inv2g[c] = rsqrtf(v + EPS);
    }
}

// ---------------------------------------------------------------------------
// Kernel 2: layer 3 gather-dot (BN2 folded into weights) + BN3 + output.
// Block = one TF t. Thread layout for the dot: half = tid>>7 picks e-parity,
// r = tid&127 picks a batch-row PAIR; each iteration loads one packed bf16x2
// (4 B/lane, fully coalesced: 64 lanes cover 128 consecutive batch rows).
// 128 loads/thread instead of 256. Halves are combined through LDS, then
// BN3 over the 256 batch rows finishes in-block.
// ---------------------------------------------------------------------------
__global__ __launch_bounds__(256) void fused3(
    const unsigned short* __restrict__ h2,  // [HID][B] bf16 bits
    const float* __restrict__ m2g,          // [HID]
    const float* __restrict__ inv2g,        // [HID]
    const float* __restrict__ w3,           // [NTF*256]
    const float* __restrict__ b3,           // [NTF]
    const int*   __restrict__ cols3,        // [NTF*256]
    float* __restrict__ out)                // [B][NTF]
{
    const int t   = blockIdx.x;
    const int tid = threadIdx.x;

    __shared__ float wls[256];
    __shared__ int   als[256];
    __shared__ float wred[4], rs[4], rs2[4];
    __shared__ float acc01[2][256];

    // fold BN2 into w3; accumulate bias correction (tid = edge index here)
    int   col = cols3[(t << 8) + tid];
    float wv  = w3[(t << 8) + tid] * inv2g[col];
    wls[tid]  = wv;
    als[tid]  = col << 8;             // col * B, bf16-element offset
    float bp  = wv * m2g[col];
    #pragma unroll
    for (int o = 32; o > 0; o >>= 1) bp += __shfl_xor(bp, o);
    if ((tid & 63) == 0) wred[tid >> 6] = bp;
    __syncthreads();

    // 256-deep dot, split: half picks e-parity, each thread covers 2 rows
    const int half = tid >> 7;
    const int r2   = (tid & 127) << 1;   // batch rows r2, r2+1
    float a0 = 0.f, a1 = 0.f;
    #pragma unroll 8
    for (int e2 = 0; e2 < 128; ++e2) {
        const int e = (e2 << 1) + half;
        float w = wls[e];
        unsigned u = *(const unsigned*)(h2 + als[e] + r2);  // bf16x2, 4B
        union { unsigned u; float f; } lo, hi;
        lo.u = u << 16;
        hi.u = u & 0xffff0000u;
        a0 = fmaf(w, lo.f, a0);
        a1 = fmaf(w, hi.f, a1);
    }
    *(float2*)&acc01[half][r2] = make_float2(a0, a1);
    __syncthreads();

    // combine halves; BN3 over the 256 batch rows (tid = batch row now)
    const float zbias = b3[t] - (wred[0] + wred[1] + wred[2] + wred[3]);
    float z = acc01[0][tid] + acc01[1][tid] + zbias;

    float s = z, s2 = z * z;
    #pragma unroll
    for (int o = 32; o > 0; o >>= 1) {
        s  += __shfl_xor(s, o);
        s2 += __shfl_xor(s2, o);
    }
    if ((tid & 63) == 0) { rs[tid >> 6] = s; rs2[tid >> 6] = s2; }
    __syncthreads();
    float S  = rs[0] + rs[1] + rs[2] + rs[3];
    float S2 = rs2[0] + rs2[1] + rs2[2] + rs2[3];
    float m  = S * (1.f / 256.f);
    float v  = fmaf(-m, m, S2 * (1.f / 256.f));
    float invs = rsqrtf(v + EPS);
    out[(size_t)tid * NTF + t] = (z - m) * invs;
}

// ---------------------------------------------------------------------------
extern "C" void kernel_launch(void* const* d_in, const int* in_sizes, int n_in,
                              void* d_out, int out_size, void* d_ws, size_t ws_size,
                              hipStream_t stream) {
    const float* x   = (const float*)d_in[0];
    const float* w1  = (const float*)d_in[1];
    const float* b1  = (const float*)d_in[2];
    const float* w2  = (const float*)d_in[3];
    const float* b2  = (const float*)d_in[4];
    const float* w3  = (const float*)d_in[5];
    const float* b3  = (const float*)d_in[6];
    const int* cols3 = (const int*)d_in[12];
    float* out = (float*)d_out;

    // workspace: h2rT [HID*B] bf16 (16.8 MB) + m2 [HID] + inv2 [HID] f32
    unsigned short* h2rT = (unsigned short*)d_ws;
    float* m2g   = (float*)(h2rT + (size_t)HID * B);
    float* inv2g = m2g + HID;

    fused12<<<HID / 64, 256, 0, stream>>>(x, w1, b1, w2, b2, h2rT, m2g, inv2g);
    fused3<<<NTF, 256, 0, stream>>>(h2rT, m2g, inv2g, w3, b3, cols3, out);
}

// Round 3
// 117.685 us; speedup vs baseline: 1.2878x; 1.0022x over previous
//
#include <hip/hip_runtime.h>
#include <cstddef>

#define EPS 1e-5f

constexpr int NG  = 8192;   // genes
constexpr int HID = 32768;  // hidden (= NG*4)
constexpr int NTF = 1024;   // TFs
constexpr int B   = 256;    // batch

// round-to-nearest-even f32 -> bf16 bits (no NaN inputs in this problem)
static __device__ __forceinline__ unsigned short f2bf(float v) {
    union { float f; unsigned u; } a; a.f = v;
    unsigned r = a.u + 0x7fffu + ((a.u >> 16) & 1u);
    return (unsigned short)(r >> 16);
}

// ---------------------------------------------------------------------------
// Kernel 1: fused  sparse-L1 -> relu -> BN1 -> sparse-L2(4x4 blockdiag) -> relu
// Writes relu(h2) TRANSPOSED [HID][B] in bf16 (coalesced gather for layer 3),
// plus per-column (mean2, invstd2) so BN2 folds into layer-3 weights.
//
// Block = 256 threads = 64 columns x 4 batch-slices of 64. BN1/BN2 stats are
// gene-local, so everything stays inside the block.
// ---------------------------------------------------------------------------
__global__ __launch_bounds__(256) void fused12(
    const float* __restrict__ x,       // [B][NG]
    const float* __restrict__ w1,      // [HID]
    const float* __restrict__ b1,      // [HID]
    const float* __restrict__ w2,      // [HID*4]
    const float* __restrict__ b2,      // [HID]
    unsigned short* __restrict__ h2rT, // [HID][B] bf16 bits
    float* __restrict__ m2g,           // [HID]
    float* __restrict__ inv2g)         // [HID]
{
    const int lane  = threadIdx.x & 63;   // column within block tile
    const int slice = threadIdx.x >> 6;   // which 64-row batch slice
    const int c     = (blockIdx.x << 6) + lane;  // global hidden column
    const int g     = c >> 2;             // gene
    const int b0    = slice << 6;

    __shared__ float redA[4][64], redB[4][64];
    __shared__ float m1s[64], inv1s[64];

    const float w1c = w1[c], b1c = b1[c];
    const float* xp = x + (size_t)b0 * NG + g;

    // ---- phase A: BN1 stats for column c over this thread's 64 rows ----
    float s = 0.f, s2 = 0.f;
    #pragma unroll 8
    for (int i = 0; i < 64; ++i) {
        float h = fmaxf(fmaf(w1c, xp[(size_t)i * NG], b1c), 0.f);
        s += h;
        s2 = fmaf(h, h, s2);
    }
    redA[slice][lane] = s;
    redB[slice][lane] = s2;
    __syncthreads();
    if (slice == 0) {
        float S  = redA[0][lane] + redA[1][lane] + redA[2][lane] + redA[3][lane];
        float S2 = redB[0][lane] + redB[1][lane] + redB[2][lane] + redB[3][lane];
        float m  = S * (1.f / 256.f);
        float v  = fmaf(-m, m, S2 * (1.f / 256.f));
        m1s[lane]   = m;
        inv1s[lane] = rsqrtf(v + EPS);
    }
    __syncthreads();

    // ---- fold BN1 into the 4x4 block weights ----
    const int lbase = lane & ~3;   // first column of my gene in LDS tile
    const int gbase = g << 2;      // first global column of my gene
    float w1j[4], b1j[4], w2s[4];
    float bconst = b2[c];
    #pragma unroll
    for (int j = 0; j < 4; ++j) {
        w1j[j] = w1[gbase + j];
        b1j[j] = b1[gbase + j];
        float wv = w2[(c << 2) + j] * inv1s[lbase + j];
        w2s[j] = wv;
        bconst = fmaf(-wv, m1s[lbase + j], bconst);
    }

    // ---- phase B: recompute h1, folded L2, relu, BN2 stats, bf16 store ----
    float t2s = 0.f, t2s2 = 0.f;
    unsigned short* op = h2rT + (size_t)c * B + b0;
    for (int i0 = 0; i0 < 64; i0 += 4) {
        ushort4 pk;
        unsigned short* pp = (unsigned short*)&pk;
        #pragma unroll
        for (int u = 0; u < 4; ++u) {
            float v = xp[(size_t)(i0 + u) * NG];
            float acc = bconst;
            #pragma unroll
            for (int j = 0; j < 4; ++j) {
                float r = fmaxf(fmaf(w1j[j], v, b1j[j]), 0.f);
                acc = fmaf(w2s[j], r, acc);
            }
            float r2 = fmaxf(acc, 0.f);
            t2s += r2;
            t2s2 = fmaf(r2, r2, t2s2);
            pp[u] = f2bf(r2);
        }
        *(ushort4*)(op + i0) = pk;   // 8 B store, aligned
    }

    __syncthreads();                 // phase-A reads of redA/redB done
    redA[slice][lane] = t2s;
    redB[slice][lane] = t2s2;
    __syncthreads();
    if (slice == 0) {
        float S  = redA[0][lane] + redA[1][lane] + redA[2][lane] + redA[3][lane];
        float S2 = redB[0][lane] + redB[1][lane] + redB[2][lane] + redB[3][lane];
        float m  = S * (1.f / 256.f);
        float v  = fmaf(-m, m, S2 * (1.f / 256.f));
        m2g[c]   = m;
        inv2g[c] = rsqrtf(v + EPS);
    }
}

// ---------------------------------------------------------------------------
// Kernel 2: layer 3 gather-dot (BN2 folded into weights) + BN3 + output.
// Block = one TF t. Dot phase: quarter = tid>>6 picks e mod 4; lane = tid&63
// covers batch rows 4*lane..4*lane+3 via ONE uint2 load (4 packed bf16).
// One wave instruction = 64 lanes x 8 B = a full 512 B column -> minimal
// vmem instruction count and full-column L2/IC requests. 64 loads/thread.
// The 4 e-quarters' partial accumulators are combined through LDS, then
// BN3 over the 256 batch rows finishes in-block.
// ---------------------------------------------------------------------------
__global__ __launch_bounds__(256) void fused3(
    const unsigned short* __restrict__ h2,  // [HID][B] bf16 bits
    const float* __restrict__ m2g,          // [HID]
    const float* __restrict__ inv2g,        // [HID]
    const float* __restrict__ w3,           // [NTF*256]
    const float* __restrict__ b3,           // [NTF]
    const int*   __restrict__ cols3,        // [NTF*256]
    float* __restrict__ out)                // [B][NTF]
{
    const int t   = blockIdx.x;
    const int tid = threadIdx.x;

    __shared__ float wls[256];
    __shared__ int   als[256];              // byte offset of column
    __shared__ float wred[4], rs[4], rs2[4];
    __shared__ float accq[4][256];

    // fold BN2 into w3; accumulate bias correction (tid = edge index here)
    int   col = cols3[(t << 8) + tid];
    float wv  = w3[(t << 8) + tid] * inv2g[col];
    wls[tid]  = wv;
    als[tid]  = col << 9;             // col * B * sizeof(bf16)
    float bp  = wv * m2g[col];
    #pragma unroll
    for (int o = 32; o > 0; o >>= 1) bp += __shfl_xor(bp, o);
    if ((tid & 63) == 0) wred[tid >> 6] = bp;
    __syncthreads();

    // 256-deep dot, 4-way e-split; each lane owns 4 batch rows
    const int q    = tid >> 6;
    const int lane = tid & 63;
    const int roff = lane << 3;        // byte offset of rows 4*lane..
    const char* h2c = (const char*)h2;
    float a0 = 0.f, a1 = 0.f, a2 = 0.f, a3 = 0.f;
    #pragma unroll 8
    for (int e2 = 0; e2 < 64; ++e2) {
        const int e = (e2 << 2) | q;
        float w = wls[e];
        uint2 u = *(const uint2*)(h2c + als[e] + roff);  // 4 bf16 rows, 8 B
        union { unsigned v; float f; } p0, p1, p2, p3;
        p0.v = u.x << 16;
        p1.v = u.x & 0xffff0000u;
        p2.v = u.y << 16;
        p3.v = u.y & 0xffff0000u;
        a0 = fmaf(w, p0.f, a0);
        a1 = fmaf(w, p1.f, a1);
        a2 = fmaf(w, p2.f, a2);
        a3 = fmaf(w, p3.f, a3);
    }
    *(float4*)&accq[q][lane << 2] = make_float4(a0, a1, a2, a3);
    __syncthreads();

    // combine quarters; BN3 over the 256 batch rows (tid = batch row now)
    const float zbias = b3[t] - (wred[0] + wred[1] + wred[2] + wred[3]);
    float z = accq[0][tid] + accq[1][tid] + accq[2][tid] + accq[3][tid] + zbias;

    float s = z, s2 = z * z;
    #pragma unroll
    for (int o = 32; o > 0; o >>= 1) {
        s  += __shfl_xor(s, o);
        s2 += __shfl_xor(s2, o);
    }
    if ((tid & 63) == 0) { rs[tid >> 6] = s; rs2[tid >> 6] = s2; }
    __syncthreads();
    float S  = rs[0] + rs[1] + rs[2] + rs[3];
    float S2 = rs2[0] + rs2[1] + rs2[2] + rs2[3];
    float m  = S * (1.f / 256.f);
    float v  = fmaf(-m, m, S2 * (1.f / 256.f));
    float invs = rsqrtf(v + EPS);
    out[(size_t)tid * NTF + t] = (z - m) * invs;
}

// ---------------------------------------------------------------------------
extern "C" void kernel_launch(void* const* d_in, const int* in_sizes, int n_in,
                              void* d_out, int out_size, void* d_ws, size_t ws_size,
                              hipStream_t stream) {
    const float* x   = (const float*)d_in[0];
    const float* w1  = (const float*)d_in[1];
    const float* b1  = (const float*)d_in[2];
    const float* w2  = (const float*)d_in[3];
    const float* b2  = (const float*)d_in[4];
    const float* w3  = (const float*)d_in[5];
    const float* b3  = (const float*)d_in[6];
    const int* cols3 = (const int*)d_in[12];
    float* out = (float*)d_out;

    // workspace: h2rT [HID*B] bf16 (16.8 MB) + m2 [HID] + inv2 [HID] f32
    unsigned short* h2rT = (unsigned short*)d_ws;
    float* m2g   = (float*)(h2rT + (size_t)HID * B);
    float* inv2g = m2g + HID;

    fused12<<<HID / 64, 256, 0, stream>>>(x, w1, b1, w2, b2, h2rT, m2g, inv2g);
    fused3<<<NTF, 256, 0, stream>>>(h2rT, m2g, inv2g, w3, b3, cols3, out);
}